// Round 4
// baseline (187.553 us; speedup 1.0000x reference)
//
#include <hip/hip_runtime.h>
#include <math.h>

#define NDIR 32
#define NH   256
#define BLK  512    // 8 waves/block
#define NB   1024   // 4 blocks/CU resident (LDS-capped), grid == capacity
#define PACKB 256   // prep grid (one max-slot per block)
#define UNIT 64     // items per work unit (1 x 64 lanes)
#define SCALE    2048.0f
#define INVSCALE (1.0 / 2048.0)
#define BIAS  128.5f   // 127.5 (ref bias) + 1.0 (ceil folded into trunc)

// ws layout in 4-byte words:
//  [8 .. 104)    : normalized dirs, 32 x 3 floats
//  [128 .. 384)  : per-block max(norm^2) slots (PACKB floats)
//  [512 .. 512+2*K0) : packed f16 vertex table (uint2 per vertex), packed path only
//  [part_off ..)     : P partial int histograms, each 32*256 int32
#define WS_DIRS 8
#define WS_BMAX 128
#define WS_TAB  512

typedef _Float16 half2v __attribute__((ext_vector_type(2)));

__device__ __forceinline__ unsigned rfl_u(unsigned x) { return __builtin_amdgcn_readfirstlane(x); }

__device__ __forceinline__ unsigned pack2(float x, float y) {
    union { half2v h; unsigned u; } c;
    c.h = half2v{(_Float16)x, (_Float16)y};   // RNE (v_cvt_f16_f32)
    return c.u;
}
__device__ __forceinline__ half2v upk(unsigned u) {
    union { unsigned u; half2v h; } c; c.u = u; return c.h;
}
__device__ __forceinline__ float hdot(half2v a, half2v b, float acc) {
#if __has_builtin(__builtin_amdgcn_fdot2)
    return __builtin_amdgcn_fdot2(a, b, acc, false);
#else
    return acc + (float)a.x * (float)b.x + (float)a.y * (float)b.y;
#endif
}
// bin = clip(trunc(hs), 0, 255); hs carries BIAS -> max+min + v_cvt_i32_f32
__device__ __forceinline__ int bin_of(float hs) {
    return (int)fminf(fmaxf(hs, 0.0f), 255.0f);
}

// prep: zero partials + normalize dirs + pack f16 table + per-block max slot (no atomics)
template <bool PACKED>
__global__ void __launch_bounds__(512) wect_prep_kernel(
    const float* __restrict__ dirs, const float* __restrict__ vc, int K0,
    int P, int part_off, float* __restrict__ ws)
{
    int tid  = blockIdx.x * blockDim.x + threadIdx.x;
    int nthr = gridDim.x * blockDim.x;
    for (int i = tid; i < P * NDIR * NH; i += nthr)
        ((int*)ws)[part_off + i] = 0;
    if (blockIdx.x == 0 && threadIdx.x >= 64 && threadIdx.x < 64 + NDIR) {
        int d = threadIdx.x - 64;
        float x = dirs[d * 3 + 0], y = dirs[d * 3 + 1], z = dirs[d * 3 + 2];
        float n = fmaxf(sqrtf(x * x + y * y + z * z), 1e-12f);
        ws[WS_DIRS + d * 3 + 0] = x / n;
        ws[WS_DIRS + d * 3 + 1] = y / n;
        ws[WS_DIRS + d * 3 + 2] = z / n;
    }
    float m = 0.0f;
    uint2* tab = (uint2*)(ws + WS_TAB);
    for (int i = tid; i < K0; i += nthr) {
        float x = vc[3 * i + 0], y = vc[3 * i + 1], z = vc[3 * i + 2];
        m = fmaxf(m, x * x + y * y + z * z);
        if (PACKED) tab[i] = make_uint2(pack2(x, y), pack2(z, 0.0f));
    }
    __shared__ float wm[8];
    #pragma unroll
    for (int off = 32; off > 0; off >>= 1)
        m = fmaxf(m, __shfl_down(m, off, 64));
    if ((threadIdx.x & 63) == 0) wm[threadIdx.x >> 6] = m;
    __syncthreads();
    if (threadIdx.x == 0) {
        float r = wm[0];
        #pragma unroll
        for (int i = 1; i < 8; ++i) r = fmaxf(r, wm[i]);
        ws[WS_BMAX + blockIdx.x] = r;
    }
}

// Unified unit space [0, Ntot): [0,N0) vertex, [N0,N01) edge, [N01,Ntot) tri.
// Block b owns the TYPE-STRIPED set {b, b+NB, ...} (identical block cost, no model).
// Waves balance within block via LDS steal counter; per wave, a 3-stage software
// pipeline keeps 3 units in flight: idx(n+2) | gathers(n+1) | compute(n), so the
// idx->gather->compute dependent-load chain (~400-800cy) hides under compute.
template <bool PACKED>
__global__ void __launch_bounds__(BLK, 8) wect_hist_kernel(
    const float* __restrict__ vc, const float* __restrict__ vw,
    const int*   __restrict__ ev, const float* __restrict__ ew,
    const int*   __restrict__ tv, const float* __restrict__ tw,
    int K0, int K1, int K2, int N0, int N01, int Ntot,
    int P, int part_off, float* __restrict__ ws)
{
    __shared__ int hist[NDIR * NH];   // 32 KB -> 4 blocks/CU (512 thr) = 32 waves/CU
    __shared__ int nctr;              // within-block work-steal cursor (LDS atomic)
    for (int i = threadIdx.x; i < (NDIR * NH) / 4; i += BLK)
        ((int4*)hist)[i] = make_int4(0, 0, 0, 0);

    const int wave = threadIdx.x >> 6;
    const int lane = threadIdx.x & 63;
    const int b    = blockIdx.x;
    const int nu   = (Ntot - b + NB - 1) / NB;   // units in this block's stripe
    if (threadIdx.x == 0) nctr = 8;              // 8 waves seed n = 0..7

    // reduce per-block max slots (wave-local, no atomics)
    float m = 0.0f;
    for (int i = lane; i < PACKB; i += 64) m = fmaxf(m, ws[WS_BMAX + i]);
    #pragma unroll
    for (int off = 32; off > 0; off >>= 1)
        m = fmaxf(m, __shfl_xor(m, off, 64));
    float maxh = fmaxf(sqrtf(m), 1e-12f);
    float inv  = 127.5f / maxh;

    // all 32 dirs per wave, packed f16 pairs pinned in SGPRs (64 SGPRs)
    unsigned sdxy[NDIR], sdz[NDIR];
    #pragma unroll
    for (int d = 0; d < NDIR; ++d) {
        float dx = ws[WS_DIRS + 3 * d + 0] * inv;
        float dy = ws[WS_DIRS + 3 * d + 1] * inv;
        float dz = ws[WS_DIRS + 3 * d + 2] * inv;
        sdxy[d] = rfl_u(pack2(dx, dy));
        sdz[d]  = rfl_u(pack2(dz, 0.0f));
    }
    __syncthreads();

    const uint2* tab = (const uint2*)(ws + WS_TAB);

    // ---- pipeline stage registers (two sets, static names: rule #20) ----
    int ia_A, ib_A, ic_A, ia_B, ib_B, ic_B;
    float wf_A = 0.0f, wf_B = 0.0f;
    half2v axy_A{}, az_A{}, bxy_A{}, bz_A{}, cxy_A{}, cz_A{};
    half2v axy_B{}, az_B{}, bxy_B{}, bz_B{}, cxy_B{}, cz_B{};
    ia_A = ib_A = ic_A = ia_B = ib_B = ic_B = 0;

    // stage 1: fetch simplex vertex indices (vertex units synthesize them)
    #define STAGE_IDX(U, S)                                                   \
        do { int u_ = (U);                                                    \
            if (u_ < N0) {                                                    \
                int i_ = u_ * UNIT + lane;                                    \
                int j_ = (i_ < K0) ? i_ : 0;                                  \
                ia_##S = j_; ib_##S = j_; ic_##S = j_;                        \
            } else if (u_ < N01) {                                            \
                int i_ = (u_ - N0) * UNIT + lane;                             \
                int j_ = (i_ < K1) ? i_ : 0;                                  \
                int2 e_ = ((const int2*)ev)[j_];                              \
                ia_##S = e_.x; ib_##S = e_.y; ic_##S = e_.y;                  \
            } else {                                                          \
                int i_ = (u_ - N01) * UNIT + lane;                            \
                int j_ = (i_ < K2) ? i_ : 0;                                  \
                ia_##S = tv[3 * j_ + 0];                                      \
                ib_##S = tv[3 * j_ + 1];                                      \
                ic_##S = tv[3 * j_ + 2];                                      \
            }                                                                 \
        } while (0)

    // stage 2: gather 3 coord rows (duplicates for v/e -> L1 hits) + weight
    #define STAGE_GATHER(U, S)                                                \
        do { int u_ = (U);                                                    \
            if constexpr (PACKED) {                                           \
                uint2 ra_ = tab[ia_##S], rb_ = tab[ib_##S], rc_ = tab[ic_##S];\
                axy_##S = upk(ra_.x); az_##S = upk(ra_.y);                    \
                bxy_##S = upk(rb_.x); bz_##S = upk(rb_.y);                    \
                cxy_##S = upk(rc_.x); cz_##S = upk(rc_.y);                    \
            } else {                                                          \
                float ax_ = vc[3 * ia_##S], ay_ = vc[3 * ia_##S + 1], azv_ = vc[3 * ia_##S + 2]; \
                float bx_ = vc[3 * ib_##S], by_ = vc[3 * ib_##S + 1], bzv_ = vc[3 * ib_##S + 2]; \
                float cx_ = vc[3 * ic_##S], cy_ = vc[3 * ic_##S + 1], czv_ = vc[3 * ic_##S + 2]; \
                axy_##S = half2v{(_Float16)ax_, (_Float16)ay_}; az_##S = half2v{(_Float16)azv_, (_Float16)0.0f}; \
                bxy_##S = half2v{(_Float16)bx_, (_Float16)by_}; bz_##S = half2v{(_Float16)bzv_, (_Float16)0.0f}; \
                cxy_##S = half2v{(_Float16)cx_, (_Float16)cy_}; cz_##S = half2v{(_Float16)czv_, (_Float16)0.0f}; \
            }                                                                 \
            if (u_ < N0) {                                                    \
                int i_ = u_ * UNIT + lane;                                    \
                wf_##S = (i_ < K0) ? vw[i_] : 0.0f;                           \
            } else if (u_ < N01) {                                            \
                int i_ = (u_ - N0) * UNIT + lane;                             \
                wf_##S = (i_ < K1) ? -ew[i_] : 0.0f;                          \
            } else {                                                          \
                int i_ = (u_ - N01) * UNIT + lane;                            \
                wf_##S = (i_ < K2) ? tw[i_] : 0.0f;                           \
            }                                                                 \
        } while (0)

    // stage 3: 32-dir dots + bin + LDS atomic (sign pre-folded into wf)
    #define STAGE_COMPUTE(U, S)                                               \
        do { int u_ = (U);                                                    \
            int w_ = __float2int_rn(wf_##S * SCALE);                          \
            if (u_ < N0) {                                                    \
                _Pragma("unroll")                                             \
                for (int d = 0; d < NDIR; ++d) {                              \
                    half2v dxy = upk(sdxy[d]), dz = upk(sdz[d]);              \
                    float h = hdot(axy_##S, dxy, hdot(az_##S, dz, BIAS));     \
                    atomicAdd(&hist[d * NH + bin_of(h)], w_);                 \
                }                                                             \
            } else if (u_ < N01) {                                            \
                _Pragma("unroll")                                             \
                for (int d = 0; d < NDIR; ++d) {                              \
                    half2v dxy = upk(sdxy[d]), dz = upk(sdz[d]);              \
                    float h = fmaxf(hdot(axy_##S, dxy, hdot(az_##S, dz, BIAS)), \
                                    hdot(bxy_##S, dxy, hdot(bz_##S, dz, BIAS))); \
                    atomicAdd(&hist[d * NH + bin_of(h)], w_);                 \
                }                                                             \
            } else {                                                          \
                _Pragma("unroll")                                             \
                for (int d = 0; d < NDIR; ++d) {                              \
                    half2v dxy = upk(sdxy[d]), dz = upk(sdz[d]);              \
                    float h = fmaxf(fmaxf(hdot(axy_##S, dxy, hdot(az_##S, dz, BIAS)), \
                                          hdot(bxy_##S, dxy, hdot(bz_##S, dz, BIAS))), \
                                    hdot(cxy_##S, dxy, hdot(cz_##S, dz, BIAS))); \
                    atomicAdd(&hist[d * NH + bin_of(h)], w_);                 \
                }                                                             \
            }                                                                 \
        } while (0)

    // ---- prologue: seed n0 (static), steal n1, n2; fill pipeline ----
    int t = 0;
    if (lane == 0) t = atomicAdd(&nctr, 1);
    int n1 = __shfl(t, 0, 64);
    if (lane == 0) t = atomicAdd(&nctr, 1);
    int n2 = __shfl(t, 0, 64);
    int n0 = wave, n3;

    if (n0 < nu) STAGE_IDX(b + n0 * NB, A);
    if (n1 < nu) STAGE_IDX(b + n1 * NB, B);
    if (n0 < nu) STAGE_GATHER(b + n0 * NB, A);   // prologue stall on A idx: ok

    // steady state: per wave, steals are monotone so n0<nu implies the tail is valid
    while (n0 < nu) {
        // phase 1: compute A
        if (n2 < nu) STAGE_IDX(b + n2 * NB, A);      // A.idx free (consumed last phase)
        if (n1 < nu) STAGE_GATHER(b + n1 * NB, B);   // B.idx loaded one phase ago
        if (lane == 0) t = atomicAdd(&nctr, 1);      // prefetch next steal
        STAGE_COMPUTE(b + n0 * NB, A);               // A rows loaded one phase ago
        n3 = __shfl(t, 0, 64);                       // DS in-order: ready by now
        n0 = n1; n1 = n2; n2 = n3;
        if (n0 >= nu) break;
        // phase 2: compute B (roles swapped)
        if (n2 < nu) STAGE_IDX(b + n2 * NB, B);
        if (n1 < nu) STAGE_GATHER(b + n1 * NB, A);
        if (lane == 0) t = atomicAdd(&nctr, 1);
        STAGE_COMPUTE(b + n0 * NB, B);
        n3 = __shfl(t, 0, 64);
        n0 = n1; n1 = n2; n2 = n3;
    }
    #undef STAGE_IDX
    #undef STAGE_GATHER
    #undef STAGE_COMPUTE

    __syncthreads();
    int* part = (int*)ws + part_off + (blockIdx.x & (P - 1)) * (NDIR * NH);
    for (int i = threadIdx.x; i < NDIR * NH; i += BLK) {
        int v = hist[i];
        if (v != 0) atomicAdd(&part[i], v);
    }
}

// one block per dir: sum P partials (int64-exact), inclusive scan over 256 bins, scale to float
__global__ void wect_reduce_kernel(const float* __restrict__ ws, int P, int part_off,
                                   float* __restrict__ out) {
    __shared__ long long s[NH];
    int d = blockIdx.x, h = threadIdx.x;
    const int* part = (const int*)ws + part_off + d * NH + h;
    long long acc = 0;
    #pragma unroll 4
    for (int p = 0; p < P; ++p)
        acc += (long long)part[p * (NDIR * NH)];
    s[h] = acc;
    __syncthreads();
    #pragma unroll
    for (int off = 1; off < NH; off <<= 1) {
        long long v = (h >= off) ? s[h - off] : 0;
        __syncthreads();
        s[h] += v;
        __syncthreads();
    }
    out[d * NH + h] = (float)((double)s[h] * INVSCALE);
}

extern "C" void kernel_launch(void* const* d_in, const int* in_sizes, int n_in,
                              void* d_out, int out_size, void* d_ws, size_t ws_size,
                              hipStream_t stream) {
    const float* dirs = (const float*)d_in[0];
    const float* vc   = (const float*)d_in[1];
    const float* vw   = (const float*)d_in[2];
    const int*   ev   = (const int*)d_in[3];
    const float* ew   = (const float*)d_in[4];
    const int*   tv   = (const int*)d_in[5];
    const float* tw   = (const float*)d_in[6];
    int K0 = in_sizes[2];
    int K1 = in_sizes[4];
    int K2 = in_sizes[6];

    float* ws  = (float*)d_ws;
    float* out = (float*)d_out;

    long long words = (long long)(ws_size / 4);

    // packed path needs table (2*K0 words) + >=8 partials
    int  part_off = WS_TAB + 2 * K0;
    bool packed   = (words - part_off) >= 8LL * NDIR * NH;
    if (!packed) part_off = WS_TAB;

    long long availP = (words - part_off) / (NDIR * NH);
    int P = 1;
    while (P * 2 <= availP && P < 16) P *= 2;   // 16 partials: enough sharding,
                                                // 4x less zero+reduce traffic

    // unified, type-striped unit space (no cost model)
    int N0 = (K0 + UNIT - 1) / UNIT;
    int N1 = (K1 + UNIT - 1) / UNIT;
    int N2 = (K2 + UNIT - 1) / UNIT;
    int N01 = N0 + N1;
    int Ntot = N01 + N2;

    if (packed) {
        wect_prep_kernel<true><<<PACKB, 512, 0, stream>>>(dirs, vc, K0, P, part_off, ws);
        wect_hist_kernel<true><<<NB, BLK, 0, stream>>>(
            vc, vw, ev, ew, tv, tw, K0, K1, K2, N0, N01, Ntot, P, part_off, ws);
    } else {
        wect_prep_kernel<false><<<PACKB, 512, 0, stream>>>(dirs, vc, K0, P, part_off, ws);
        wect_hist_kernel<false><<<NB, BLK, 0, stream>>>(
            vc, vw, ev, ew, tv, tw, K0, K1, K2, N0, N01, Ntot, P, part_off, ws);
    }
    wect_reduce_kernel<<<NDIR, NH, 0, stream>>>(ws, P, part_off, out);
}

// Round 5
// 65.931 us; speedup vs baseline: 2.8447x; 2.8447x over previous
//
#include <hip/hip_runtime.h>
#include <math.h>

#define NDIR 32
#define NH   256
#define BLK  512    // 8 waves/block
#define NB   1024   // 4 blocks/CU resident (LDS-capped), grid == capacity
#define PACKB 256   // prep grid (one max-slot per block)
#define UNIT 64     // items per work unit (1 x 64 lanes)
#define SCALE    2048.0f
#define INVSCALE (1.0 / 2048.0)
#define BIAS  128.5f   // 127.5 (ref bias) + 1.0 (ceil folded into trunc)

// ws layout in 4-byte words:
//  [8 .. 104)    : normalized dirs, 32 x 3 floats
//  [128 .. 384)  : per-block max(norm^2) slots (PACKB floats)
//  [512 .. 512+2*K0) : packed f16 vertex table (uint2 per vertex), packed path only
//  [part_off ..)     : P partial int histograms, each 32*256 int32
#define WS_DIRS 8
#define WS_BMAX 128
#define WS_TAB  512

typedef _Float16 half2v __attribute__((ext_vector_type(2)));

__device__ __forceinline__ unsigned rfl_u(unsigned x) { return __builtin_amdgcn_readfirstlane(x); }
__device__ __forceinline__ int      rfl_i(int x)      { return __builtin_amdgcn_readfirstlane(x); }

__device__ __forceinline__ unsigned pack2(float x, float y) {
    union { half2v h; unsigned u; } c;
    c.h = half2v{(_Float16)x, (_Float16)y};   // RNE (v_cvt_f16_f32)
    return c.u;
}
__device__ __forceinline__ half2v upk(unsigned u) {
    union { unsigned u; half2v h; } c; c.u = u; return c.h;
}
__device__ __forceinline__ float hdot(half2v a, half2v b, float acc) {
#if __has_builtin(__builtin_amdgcn_fdot2)
    return __builtin_amdgcn_fdot2(a, b, acc, false);
#else
    return acc + (float)a.x * (float)b.x + (float)a.y * (float)b.y;
#endif
}
// bin = clip(trunc(hs), 0, 255); hs carries BIAS -> max+min + v_cvt_i32_f32
__device__ __forceinline__ int bin_of(float hs) {
    return (int)fminf(fmaxf(hs, 0.0f), 255.0f);
}

// prep: zero partials + normalize dirs + pack f16 table + per-block max slot (no atomics)
template <bool PACKED>
__global__ void __launch_bounds__(512) wect_prep_kernel(
    const float* __restrict__ dirs, const float* __restrict__ vc, int K0,
    int P, int part_off, float* __restrict__ ws)
{
    int tid  = blockIdx.x * blockDim.x + threadIdx.x;
    int nthr = gridDim.x * blockDim.x;
    for (int i = tid; i < P * NDIR * NH; i += nthr)
        ((int*)ws)[part_off + i] = 0;
    if (blockIdx.x == 0 && threadIdx.x >= 64 && threadIdx.x < 64 + NDIR) {
        int d = threadIdx.x - 64;
        float x = dirs[d * 3 + 0], y = dirs[d * 3 + 1], z = dirs[d * 3 + 2];
        float n = fmaxf(sqrtf(x * x + y * y + z * z), 1e-12f);
        ws[WS_DIRS + d * 3 + 0] = x / n;
        ws[WS_DIRS + d * 3 + 1] = y / n;
        ws[WS_DIRS + d * 3 + 2] = z / n;
    }
    float m = 0.0f;
    uint2* tab = (uint2*)(ws + WS_TAB);
    for (int i = tid; i < K0; i += nthr) {
        float x = vc[3 * i + 0], y = vc[3 * i + 1], z = vc[3 * i + 2];
        m = fmaxf(m, x * x + y * y + z * z);
        if (PACKED) tab[i] = make_uint2(pack2(x, y), pack2(z, 0.0f));
    }
    __shared__ float wm[8];
    #pragma unroll
    for (int off = 32; off > 0; off >>= 1)
        m = fmaxf(m, __shfl_down(m, off, 64));
    if ((threadIdx.x & 63) == 0) wm[threadIdx.x >> 6] = m;
    __syncthreads();
    if (threadIdx.x == 0) {
        float r = wm[0];
        #pragma unroll
        for (int i = 1; i < 8; ++i) r = fmaxf(r, wm[i]);
        ws[WS_BMAX + blockIdx.x] = r;
    }
}

// Unified unit space [0, Ntot): [0,N0) vertex, [N0,N01) edge, [N01,Ntot) tri.
// Block b owns the type-striped set {b, b+NB, ...}; since u=b+n*NB is monotone in
// n, the stripe is THREE CONTIGUOUS SEGMENTS (vertex | edge | tri). One monotone
// LDS steal counter balances waves; each segment runs a type-SPECIALIZED loop with
// a small software pipeline (vertex depth-2; edge/tri depth-3: idx(n2)|gather(n1)|
// compute(n0)), so the idx->gather->compute chain hides under compute without the
// giant branchy register sets that spilled in the previous attempt.
template <bool PACKED>
__global__ void __launch_bounds__(BLK, 8) wect_hist_kernel(
    const float* __restrict__ vc, const float* __restrict__ vw,
    const int*   __restrict__ ev, const float* __restrict__ ew,
    const int*   __restrict__ tv, const float* __restrict__ tw,
    int K0, int K1, int K2, int N0, int N01, int Ntot,
    int P, int part_off, float* __restrict__ ws)
{
    __shared__ int hist[NDIR * NH];   // 32 KB -> 4 blocks/CU (512 thr) = 32 waves/CU
    __shared__ int nctr;              // within-block work-steal cursor (LDS atomic)
    for (int i = threadIdx.x; i < (NDIR * NH) / 4; i += BLK)
        ((int4*)hist)[i] = make_int4(0, 0, 0, 0);

    const int wave = threadIdx.x >> 6;
    const int lane = threadIdx.x & 63;
    const int b    = blockIdx.x;
    const int nu   = (Ntot - b + NB - 1) / NB;                 // stripe length
    const int e0   = (N0  > b) ? (N0  - b + NB - 1) / NB : 0;  // vertex segment end
    const int e1   = (N01 > b) ? (N01 - b + NB - 1) / NB : 0;  // edge segment end
    if (threadIdx.x == 0) nctr = 8;                            // waves seed n=0..7

    // reduce per-block max slots (wave-local, no atomics)
    float m = 0.0f;
    for (int i = lane; i < PACKB; i += 64) m = fmaxf(m, ws[WS_BMAX + i]);
    #pragma unroll
    for (int off = 32; off > 0; off >>= 1)
        m = fmaxf(m, __shfl_xor(m, off, 64));
    float maxh = fmaxf(sqrtf(m), 1e-12f);
    float inv  = 127.5f / maxh;

    // all 32 dirs per wave, packed f16 pairs pinned in SGPRs (64 SGPRs)
    unsigned sdxy[NDIR], sdz[NDIR];
    #pragma unroll
    for (int d = 0; d < NDIR; ++d) {
        float dx = ws[WS_DIRS + 3 * d + 0] * inv;
        float dy = ws[WS_DIRS + 3 * d + 1] * inv;
        float dz = ws[WS_DIRS + 3 * d + 2] * inv;
        sdxy[d] = rfl_u(pack2(dx, dy));
        sdz[d]  = rfl_u(pack2(dz, 0.0f));
    }
    __syncthreads();

    const uint2* tab = (const uint2*)(ws + WS_TAB);
    // load one packed coord row
    #define LROW(J, XY, Z)                                                    \
        do {                                                                  \
            if constexpr (PACKED) {                                           \
                uint2 r_ = tab[J]; XY = upk(r_.x); Z = upk(r_.y);             \
            } else {                                                          \
                float x_ = vc[3 * (J)], y_ = vc[3 * (J) + 1], z_ = vc[3 * (J) + 2]; \
                XY = half2v{(_Float16)x_, (_Float16)y_};                      \
                Z  = half2v{(_Float16)z_, (_Float16)0.0f};                    \
            }                                                                 \
        } while (0)

    #define STEAL() do { if (lane == 0) t = atomicAdd(&nctr, 1); } while (0)

    // ---- claimed-unit queue (wave-uniform, monotone) ----
    int t = 0, n0 = wave, n1, n2;
    STEAL(); n1 = rfl_i(t);
    STEAL(); n2 = rfl_i(t);

    // ================= segment 0: vertices (depth-2, affine idx) =============
    {
        half2v xyA{}, zA{}, xyB{}, zB{};
        float wA = 0.0f, wB = 0.0f;
        #define VGATH(N, S)                                                   \
            do { int i_ = (b + (N) * NB) * UNIT + lane;                       \
                 int j_ = (i_ < K0) ? i_ : 0;                                 \
                 LROW(j_, xy##S, z##S);                                       \
                 w##S = (i_ < K0) ? vw[j_] : 0.0f; } while (0)
        #define VCOMP(S)                                                      \
            do { int wi_ = __float2int_rn(w##S * SCALE);                      \
                 _Pragma("unroll")                                            \
                 for (int d = 0; d < NDIR; ++d) {                             \
                     half2v dxy = upk(sdxy[d]), dz = upk(sdz[d]);             \
                     float h = hdot(xy##S, dxy, hdot(z##S, dz, BIAS));        \
                     atomicAdd(&hist[d * NH + bin_of(h)], wi_);               \
                 } } while (0)
        if (n0 < e0) VGATH(n0, A);
        while (n0 < e0) {
            if (n1 < e0) VGATH(n1, B);
            STEAL();
            VCOMP(A);
            n0 = n1; n1 = n2; n2 = rfl_i(t);
            if (n0 >= e0) break;
            if (n1 < e0) VGATH(n1, A);
            STEAL();
            VCOMP(B);
            n0 = n1; n1 = n2; n2 = rfl_i(t);
        }
        #undef VGATH
        #undef VCOMP
    }

    // ================= segment 1: edges (depth-3, sign -1) ===================
    {
        int iaA = 0, ibA = 0, iaB = 0, ibB = 0;
        half2v axyA{}, azA{}, bxyA{}, bzA{};
        half2v axyB{}, azB{}, bxyB{}, bzB{};
        float wA = 0.0f, wB = 0.0f;
        #define EIDX(N, S)                                                    \
            do { int i_ = (b + (N) * NB - N0) * UNIT + lane;                  \
                 int j_ = (i_ < K1) ? i_ : 0;                                 \
                 int2 e_ = ((const int2*)ev)[j_];                             \
                 ia##S = e_.x; ib##S = e_.y; } while (0)
        #define EGATH(N, S)                                                   \
            do { LROW(ia##S, axy##S, az##S);                                  \
                 LROW(ib##S, bxy##S, bz##S);                                  \
                 int i_ = (b + (N) * NB - N0) * UNIT + lane;                  \
                 w##S = (i_ < K1) ? -ew[i_] : 0.0f; } while (0)
        #define ECOMP(S)                                                      \
            do { int wi_ = __float2int_rn(w##S * SCALE);                      \
                 _Pragma("unroll")                                            \
                 for (int d = 0; d < NDIR; ++d) {                             \
                     half2v dxy = upk(sdxy[d]), dz = upk(sdz[d]);             \
                     float h = fmaxf(hdot(axy##S, dxy, hdot(az##S, dz, BIAS)),\
                                     hdot(bxy##S, dxy, hdot(bz##S, dz, BIAS)));\
                     atomicAdd(&hist[d * NH + bin_of(h)], wi_);               \
                 } } while (0)
        if (n0 < e1) EIDX(n0, A);
        if (n1 < e1) EIDX(n1, B);
        if (n0 < e1) EGATH(n0, A);
        while (n0 < e1) {
            if (n1 < e1) EGATH(n1, B);
            if (n2 < e1) EIDX(n2, A);
            STEAL();
            ECOMP(A);
            n0 = n1; n1 = n2; n2 = rfl_i(t);
            if (n0 >= e1) break;
            if (n1 < e1) EGATH(n1, A);
            if (n2 < e1) EIDX(n2, B);
            STEAL();
            ECOMP(B);
            n0 = n1; n1 = n2; n2 = rfl_i(t);
        }
        #undef EIDX
        #undef EGATH
        #undef ECOMP
    }

    // ================= segment 2: triangles (depth-3, sign +1) ===============
    {
        int iaA = 0, ibA = 0, icA = 0, iaB = 0, ibB = 0, icB = 0;
        half2v axyA{}, azA{}, bxyA{}, bzA{}, cxyA{}, czA{};
        half2v axyB{}, azB{}, bxyB{}, bzB{}, cxyB{}, czB{};
        float wA = 0.0f, wB = 0.0f;
        #define TIDX(N, S)                                                    \
            do { int i_ = (b + (N) * NB - N01) * UNIT + lane;                 \
                 int j_ = (i_ < K2) ? i_ : 0;                                 \
                 ia##S = tv[3 * j_ + 0];                                      \
                 ib##S = tv[3 * j_ + 1];                                      \
                 ic##S = tv[3 * j_ + 2]; } while (0)
        #define TGATH(N, S)                                                   \
            do { LROW(ia##S, axy##S, az##S);                                  \
                 LROW(ib##S, bxy##S, bz##S);                                  \
                 LROW(ic##S, cxy##S, cz##S);                                  \
                 int i_ = (b + (N) * NB - N01) * UNIT + lane;                 \
                 w##S = (i_ < K2) ? tw[i_] : 0.0f; } while (0)
        #define TCOMP(S)                                                      \
            do { int wi_ = __float2int_rn(w##S * SCALE);                      \
                 _Pragma("unroll")                                            \
                 for (int d = 0; d < NDIR; ++d) {                             \
                     half2v dxy = upk(sdxy[d]), dz = upk(sdz[d]);             \
                     float h = fmaxf(fmaxf(hdot(axy##S, dxy, hdot(az##S, dz, BIAS)),  \
                                           hdot(bxy##S, dxy, hdot(bz##S, dz, BIAS))), \
                                     hdot(cxy##S, dxy, hdot(cz##S, dz, BIAS)));\
                     atomicAdd(&hist[d * NH + bin_of(h)], wi_);               \
                 } } while (0)
        if (n0 < nu) TIDX(n0, A);
        if (n1 < nu) TIDX(n1, B);
        if (n0 < nu) TGATH(n0, A);
        while (n0 < nu) {
            if (n1 < nu) TGATH(n1, B);
            if (n2 < nu) TIDX(n2, A);
            STEAL();
            TCOMP(A);
            n0 = n1; n1 = n2; n2 = rfl_i(t);
            if (n0 >= nu) break;
            if (n1 < nu) TGATH(n1, A);
            if (n2 < nu) TIDX(n2, B);
            STEAL();
            TCOMP(B);
            n0 = n1; n1 = n2; n2 = rfl_i(t);
        }
        #undef TIDX
        #undef TGATH
        #undef TCOMP
    }
    #undef LROW
    #undef STEAL

    __syncthreads();
    int* part = (int*)ws + part_off + (blockIdx.x & (P - 1)) * (NDIR * NH);
    for (int i = threadIdx.x; i < NDIR * NH; i += BLK) {
        int v = hist[i];
        if (v != 0) atomicAdd(&part[i], v);
    }
}

// one block per dir: sum P partials (int64-exact), inclusive scan over 256 bins, scale to float
__global__ void wect_reduce_kernel(const float* __restrict__ ws, int P, int part_off,
                                   float* __restrict__ out) {
    __shared__ long long s[NH];
    int d = blockIdx.x, h = threadIdx.x;
    const int* part = (const int*)ws + part_off + d * NH + h;
    long long acc = 0;
    #pragma unroll 4
    for (int p = 0; p < P; ++p)
        acc += (long long)part[p * (NDIR * NH)];
    s[h] = acc;
    __syncthreads();
    #pragma unroll
    for (int off = 1; off < NH; off <<= 1) {
        long long v = (h >= off) ? s[h - off] : 0;
        __syncthreads();
        s[h] += v;
        __syncthreads();
    }
    out[d * NH + h] = (float)((double)s[h] * INVSCALE);
}

extern "C" void kernel_launch(void* const* d_in, const int* in_sizes, int n_in,
                              void* d_out, int out_size, void* d_ws, size_t ws_size,
                              hipStream_t stream) {
    const float* dirs = (const float*)d_in[0];
    const float* vc   = (const float*)d_in[1];
    const float* vw   = (const float*)d_in[2];
    const int*   ev   = (const int*)d_in[3];
    const float* ew   = (const float*)d_in[4];
    const int*   tv   = (const int*)d_in[5];
    const float* tw   = (const float*)d_in[6];
    int K0 = in_sizes[2];
    int K1 = in_sizes[4];
    int K2 = in_sizes[6];

    float* ws  = (float*)d_ws;
    float* out = (float*)d_out;

    long long words = (long long)(ws_size / 4);

    // packed path needs table (2*K0 words) + >=8 partials
    int  part_off = WS_TAB + 2 * K0;
    bool packed   = (words - part_off) >= 8LL * NDIR * NH;
    if (!packed) part_off = WS_TAB;

    long long availP = (words - part_off) / (NDIR * NH);
    int P = 1;
    while (P * 2 <= availP && P < 16) P *= 2;   // 16 partials: enough sharding,
                                                // 4x less zero+reduce traffic

    // unified, type-striped unit space (no cost model)
    int N0 = (K0 + UNIT - 1) / UNIT;
    int N1 = (K1 + UNIT - 1) / UNIT;
    int N2 = (K2 + UNIT - 1) / UNIT;
    int N01 = N0 + N1;
    int Ntot = N01 + N2;

    if (packed) {
        wect_prep_kernel<true><<<PACKB, 512, 0, stream>>>(dirs, vc, K0, P, part_off, ws);
        wect_hist_kernel<true><<<NB, BLK, 0, stream>>>(
            vc, vw, ev, ew, tv, tw, K0, K1, K2, N0, N01, Ntot, P, part_off, ws);
    } else {
        wect_prep_kernel<false><<<PACKB, 512, 0, stream>>>(dirs, vc, K0, P, part_off, ws);
        wect_hist_kernel<false><<<NB, BLK, 0, stream>>>(
            vc, vw, ev, ew, tv, tw, K0, K1, K2, N0, N01, Ntot, P, part_off, ws);
    }
    wect_reduce_kernel<<<NDIR, NH, 0, stream>>>(ws, P, part_off, out);
}